// Round 4
// baseline (1613.632 us; speedup 1.0000x reference)
//
#include <hip/hip_runtime.h>
#include <hip/hip_bf16.h>
#include <stdint.h>

// Problem constants
#define TT 4
#define BE 16
#define BB 64          // TT * BE
#define CC 512
#define NN 512
#define NH 8
#define GD 64          // CC / NH
#define NW 16          // NN/32 packed words per (b,c) row
#define TAU 0.5f
#define THRESH 1.0f
#define SCALE 0.125f
#define EPS 1e-5f

// Direct global->LDS DMA, 16B per lane. LDS dest is wave-uniform base +
// lane*16 (linear); global src is per-lane.
#define GLL16(g, l)                                                        \
    __builtin_amdgcn_global_load_lds(                                      \
        (const __attribute__((address_space(1))) void*)(g),                \
        (__attribute__((address_space(3))) void*)(l), 16, 0, 0)

// ---------------------------------------------------------------------------
// Kernel 1 v5: 1x1-conv + BN + LIF -> bit-packed spikes.
// History: v1 775us (VGPR=128, stall ~1100cyc/stage: loads issued AND drained
// in the same inter-barrier region). v2 launch_bounds disaster. v3 164 VGPR
// (merged-region hoisting). v4 136 VGPR (+8 = live W prefetch pair) + mid-
// compute sched_barrier -> 1034us.
// v5 idea: issue next tile's global_load_lds INSIDE the compute region of the
// current tile. __syncthreads drains vmcnt(0) -- but the NEXT stage's first
// barrier is a full compute phase (~1024 cyc) after issue, so the drain is
// free. Alias conservatism (gll writes Xs, compute reads Xs) pins the glls
// above the ds_reads; no sched_barrier needed. gll needs no result VGPRs
// (-8 X temps vs v1, +4 W float4) -> ~124 VGPR, under the 128 cliff.
// Per stage: [gll->buf^1, load Wnext | compute buf] syncA; Ws<-Wnext; syncB.
// Block tile: 64 c-rows x 128 n-cols, 256 threads, micro-tile 4x8.
// ---------------------------------------------------------------------------
__global__ __launch_bounds__(256) void conv_bn_lif_kernel(
    const float* __restrict__ x,      // [BB, CC, NN]
    const float* __restrict__ Wq,     // [CC, CC] (out, in)
    const float* __restrict__ Wk,
    const float* __restrict__ Wv,
    const float* __restrict__ bn_g,   // [4, CC]
    const float* __restrict__ bn_b,
    const float* __restrict__ bn_m,
    const float* __restrict__ bn_v,
    uint32_t* __restrict__ qp,        // [BB*CC, NW] packed
    uint32_t* __restrict__ kp,
    uint32_t* __restrict__ vp)
{
    // Xs UNPADDED [16][128] x2 (linear layout required by global_load_lds).
    // float4 reads at 4*tx (+64) are 2-way bank aliasing max = free.
    __shared__ float Xs[2][16][128];   // 16 KB
    __shared__ float Ws_s[16][68];     // 4.3 KB -> total ~21 KB, 4 blocks/CU

    const int tid = threadIdx.x;
    const int tx = tid & 15;          // col group
    const int ty = tid >> 4;          // row group: rows c0+4ty..+3
    const int n0 = blockIdx.x * 128;
    const int c0 = blockIdx.y * 64;
    const int z  = blockIdx.z;
    const int be = z & (BE - 1);
    const int w  = z >> 4;            // 0=q 1=k 2=v

    const float* W = (w == 0) ? Wq : (w == 1) ? Wk : Wv;
    uint32_t* outp = (w == 0) ? qp : (w == 1) ? kp : vp;

    float inv_c[4], add_c[4];
#pragma unroll
    for (int i = 0; i < 4; ++i) {
        int c = c0 + 4 * ty + i;
        float g = bn_g[w * CC + c];
        float b = bn_b[w * CC + c];
        float m = bn_m[w * CC + c];
        float v = bn_v[w * CC + c];
        float inv = g / sqrtf(v + EPS);
        inv_c[i] = inv;
        add_c[i] = b - m * inv;
    }

    float mem[4][8];
#pragma unroll
    for (int i = 0; i < 4; ++i)
#pragma unroll
        for (int j = 0; j < 8; ++j) mem[i][j] = 0.0f;

    // W staging mapping (reg->LDS transpose; gll can't transpose)
    const int wr  = tid >> 2;         // W row within tile (0..63)
    const int wkw = tid & 3;          // W float4 along K
    const float* Wrow = W + (size_t)(c0 + wr) * CC + 4 * wkw;

    // X gll mapping: wave wid stages rows {2wid+(lane>>5)} and +8;
    // lane covers 16B at col 4*(lane&31). Dest base is wave-uniform.
    const int lane = tid & 63;
    const int wid  = tid >> 6;
    const int xrow = 2 * wid + (lane >> 5);
    const int xcol = 4 * (lane & 31);

    for (int t = 0; t < TT; ++t) {
        const int b = t * BE + be;
        const float* xg = x + (size_t)b * CC * NN + n0 + xcol;

        __syncthreads();   // seal prev-t readers of Ws / buf0
        // ---- per-t prologue: stage k0=0 (latency exposed once per t) ----
        {
            float4 w0 = *(const float4*)&Wrow[0];   // issued first: Ws write
                                                    // waits only vmcnt(2)
            GLL16(xg + (size_t)xrow * NN,       &Xs[0][2 * wid][0]);
            GLL16(xg + (size_t)(xrow + 8) * NN, &Xs[0][2 * wid + 8][0]);
            Ws_s[4 * wkw + 0][wr] = w0.x;
            Ws_s[4 * wkw + 1][wr] = w0.y;
            Ws_s[4 * wkw + 2][wr] = w0.z;
            Ws_s[4 * wkw + 3][wr] = w0.w;
        }
        __syncthreads();   // buf0 + Ws ready

        float acc[4][8];
#pragma unroll
        for (int i = 0; i < 4; ++i)
#pragma unroll
            for (int j = 0; j < 8; ++j) acc[i][j] = 0.0f;

        int cur = 0;
        for (int k0 = 0; k0 < CC; k0 += 16) {
            const bool more = (k0 + 16 < CC);
            float4 wnext;
            if (more) {
                // issue next tile INSIDE this compute region: drained at the
                // NEXT stage's syncA, i.e. hidden under the 16-kk compute.
                GLL16(xg + (size_t)(k0 + 16 + xrow) * NN,
                      &Xs[cur ^ 1][2 * wid][0]);
                GLL16(xg + (size_t)(k0 + 16 + xrow + 8) * NN,
                      &Xs[cur ^ 1][2 * wid + 8][0]);
                wnext = *(const float4*)&Wrow[k0 + 16];
            }

            // ---- compute current buffer ----
#pragma unroll
            for (int kk = 0; kk < 16; ++kk) {
                float4 av  = *(float4*)&Ws_s[kk][4 * ty];      // broadcast
                float4 xlo = *(float4*)&Xs[cur][kk][4 * tx];   // 2-way
                float4 xhi = *(float4*)&Xs[cur][kk][64 + 4 * tx];
                const float a[4]  = {av.x, av.y, av.z, av.w};
                const float xl[4] = {xlo.x, xlo.y, xlo.z, xlo.w};
                const float xh[4] = {xhi.x, xhi.y, xhi.z, xhi.w};
#pragma unroll
                for (int i = 0; i < 4; ++i) {
#pragma unroll
                    for (int j = 0; j < 4; ++j) {
                        acc[i][j]     += a[i] * xl[j];
                        acc[i][4 + j] += a[i] * xh[j];
                    }
                }
            }

            if (more) {
                __syncthreads();   // syncA: drains glls (already complete)
                Ws_s[4 * wkw + 0][wr] = wnext.x;
                Ws_s[4 * wkw + 1][wr] = wnext.y;
                Ws_s[4 * wkw + 2][wr] = wnext.z;
                Ws_s[4 * wkw + 3][wr] = wnext.w;
                __syncthreads();   // syncB: lgkm drain only (cheap)
                cur ^= 1;
            }
        }

        // epilogue: BN + LIF -> two nibbles/row -> octet shfl-OR -> global word
#pragma unroll
        for (int i = 0; i < 4; ++i) {
            uint32_t nibLo = 0, nibHi = 0;
#pragma unroll
            for (int j = 0; j < 4; ++j) {
                float y = acc[i][j] * inv_c[i] + add_c[i];
                float m2 = mem[i][j] * TAU + y;
                bool s = m2 > THRESH;
                nibLo |= (s ? 1u : 0u) << j;
                mem[i][j] = s ? 0.0f : m2;

                float y2 = acc[i][4 + j] * inv_c[i] + add_c[i];
                float m22 = mem[i][4 + j] * TAU + y2;
                bool s2 = m22 > THRESH;
                nibHi |= (s2 ? 1u : 0u) << j;
                mem[i][4 + j] = s2 ? 0.0f : m22;
            }
            const size_t rowbase = (size_t)(b * CC + c0 + 4 * ty + i) * NW + (n0 >> 5);
            uint32_t wlo = nibLo << (4 * (tx & 7));
            wlo |= (uint32_t)__shfl_xor((int)wlo, 1);
            wlo |= (uint32_t)__shfl_xor((int)wlo, 2);
            wlo |= (uint32_t)__shfl_xor((int)wlo, 4);
            uint32_t whi = nibHi << (4 * (tx & 7));
            whi |= (uint32_t)__shfl_xor((int)whi, 1);
            whi |= (uint32_t)__shfl_xor((int)whi, 2);
            whi |= (uint32_t)__shfl_xor((int)whi, 4);
            if ((tx & 7) == 0) {
                outp[rowbase + (tx >> 3)] = wlo;
                outp[rowbase + 2 + (tx >> 3)] = whi;
            }
        }
    }
}

// ---------------------------------------------------------------------------
// Kernel 2: fused attention + LIF3 on packed spikes (unchanged, verified).
// ---------------------------------------------------------------------------
__global__ __launch_bounds__(256) void attn_lif_kernel(
    const uint32_t* __restrict__ qp,
    const uint32_t* __restrict__ kp,
    const uint32_t* __restrict__ vp,
    uint32_t* __restrict__ s3p)
{
    __shared__ uint32_t kL[64][NW + 1];
    __shared__ uint32_t vL[64][NW + 1];
    __shared__ float    Msh[64][64 + 1];
    __shared__ uint32_t qL[64][5];

    const int tid = threadIdx.x;
    const int nchunk = blockIdx.x;
    const int h = blockIdx.y;
    const int be = blockIdx.z;
    const int d_own = tid >> 2;
    const int nw_own = tid & 3;

    float mem[32];
#pragma unroll
    for (int i = 0; i < 32; ++i) mem[i] = 0.0f;

    for (int t = 0; t < TT; ++t) {
        const int b = t * BE + be;
        const size_t base_row = (size_t)(b * CC + h * GD);

        for (int i = tid; i < 64 * NW; i += 256) {
            int r = i >> 4;
            int w = i & (NW - 1);
            kL[r][w] = kp[(base_row + r) * NW + w];
            vL[r][w] = vp[(base_row + r) * NW + w];
        }
        {
            int r = tid >> 2;
            int w = tid & 3;
            qL[r][w] = qp[(base_row + r) * NW + nchunk * 4 + w];
        }
        __syncthreads();

        for (int e = tid; e < 64 * 64; e += 256) {
            int d = e >> 6;
            int dp = e & 63;
            int s = 0;
#pragma unroll
            for (int w = 0; w < NW; ++w) s += __popc(vL[d][w] & kL[dp][w]);
            Msh[d][dp] = (float)s;
        }
        __syncthreads();

        float acc[32];
#pragma unroll
        for (int i = 0; i < 32; ++i) acc[i] = 0.0f;

        for (int dp = 0; dp < 64; ++dp) {
            float Mv = Msh[d_own][dp];
            uint32_t w = qL[dp][nw_own];
#pragma unroll
            for (int b2 = 0; b2 < 32; ++b2) {
                acc[b2] += ((w >> b2) & 1u) ? Mv : 0.0f;
            }
        }

        uint32_t sw = 0;
#pragma unroll
        for (int b2 = 0; b2 < 32; ++b2) {
            float m2 = mem[b2] * TAU + SCALE * acc[b2];
            bool s = m2 > THRESH;
            sw |= (s ? 1u : 0u) << b2;
            mem[b2] = s ? 0.0f : m2;
        }
        s3p[(base_row + d_own) * NW + nchunk * 4 + nw_own] = sw;
        __syncthreads();
    }
}

// ---------------------------------------------------------------------------
// Kernel 3 (kept from round 2 — improved there, VGPR under the cliff):
// projection conv + BN on packed spikes -> fp32 output. Double-buffered,
// 1 barrier per k-step, reg-staged (tiny prefetch state).
// ---------------------------------------------------------------------------
__global__ __launch_bounds__(256) void proj_kernel(
    const uint32_t* __restrict__ s3p,          // [BB*CC, NW] packed
    const float* __restrict__ W,               // [CC, CC]
    const float* __restrict__ bn_g,
    const float* __restrict__ bn_b,
    const float* __restrict__ bn_m,
    const float* __restrict__ bn_v,
    float* __restrict__ out)                   // [BB, CC, NN]
{
    __shared__ float Xs[2][16][132];
    __shared__ float Ws_s[2][16][68];

    const int tid = threadIdx.x;
    const int tx = tid & 15;
    const int ty = tid >> 4;
    const int n0 = blockIdx.x * 128;
    const int c0 = blockIdx.y * 64;
    const int b = blockIdx.z;

    float inv_c[4], add_c[4];
#pragma unroll
    for (int i = 0; i < 4; ++i) {
        int c = c0 + 4 * ty + i;
        float g = bn_g[3 * CC + c];
        float bt = bn_b[3 * CC + c];
        float m = bn_m[3 * CC + c];
        float v = bn_v[3 * CC + c];
        float inv = g / sqrtf(v + EPS);
        inv_c[i] = inv;
        add_c[i] = bt - m * inv;
    }

    const int wr  = tid >> 2;
    const int wkw = tid & 3;
    const int kkA = tid >> 5;
    const int colA = tid & 31;
    const int shA = 4 * (colA & 7);

    const float* Wrow = W + (size_t)(c0 + wr) * CC + 4 * wkw;
    const uint32_t* sp = s3p + (size_t)(b * CC) * NW + (n0 >> 5) + (colA >> 3);

    float acc[4][8];
#pragma unroll
    for (int i = 0; i < 4; ++i)
#pragma unroll
        for (int j = 0; j < 8; ++j) acc[i][j] = 0.0f;

    // ---- prologue: stage k0=0 into buf0 (latency exposed once) ----
    {
        uint32_t swA = sp[(size_t)kkA * NW];
        uint32_t swB = sp[(size_t)(8 + kkA) * NW];
        float4 wv4 = *(const float4*)&Wrow[0];
        float4 xv;
        xv.x = (float)((swA >> (shA + 0)) & 1u);
        xv.y = (float)((swA >> (shA + 1)) & 1u);
        xv.z = (float)((swA >> (shA + 2)) & 1u);
        xv.w = (float)((swA >> (shA + 3)) & 1u);
        *(float4*)&Xs[0][kkA][4 * colA] = xv;
        xv.x = (float)((swB >> (shA + 0)) & 1u);
        xv.y = (float)((swB >> (shA + 1)) & 1u);
        xv.z = (float)((swB >> (shA + 2)) & 1u);
        xv.w = (float)((swB >> (shA + 3)) & 1u);
        *(float4*)&Xs[0][8 + kkA][4 * colA] = xv;
        Ws_s[0][4 * wkw + 0][wr] = wv4.x;
        Ws_s[0][4 * wkw + 1][wr] = wv4.y;
        Ws_s[0][4 * wkw + 2][wr] = wv4.z;
        Ws_s[0][4 * wkw + 3][wr] = wv4.w;
    }
    __syncthreads();

    int cur = 0;
    for (int k0 = 0; k0 < CC; k0 += 16) {
        const int nxt = cur ^ 1;
        uint32_t swA, swB;
        float4 wv4;
        if (k0 + 16 < CC) {
            swA = sp[(size_t)(k0 + 16 + kkA) * NW];
            swB = sp[(size_t)(k0 + 24 + kkA) * NW];
            wv4 = *(const float4*)&Wrow[k0 + 16];
        }

#pragma unroll
        for (int kk = 0; kk < 16; ++kk) {
            float4 av  = *(float4*)&Ws_s[cur][kk][4 * ty];
            float4 xlo = *(float4*)&Xs[cur][kk][4 * tx];
            float4 xhi = *(float4*)&Xs[cur][kk][64 + 4 * tx];
            const float a[4]  = {av.x, av.y, av.z, av.w};
            const float xl[4] = {xlo.x, xlo.y, xlo.z, xlo.w};
            const float xh[4] = {xhi.x, xhi.y, xhi.z, xhi.w};
#pragma unroll
            for (int i = 0; i < 4; ++i) {
#pragma unroll
                for (int j = 0; j < 4; ++j) {
                    acc[i][j]     += a[i] * xl[j];
                    acc[i][4 + j] += a[i] * xh[j];
                }
            }
        }

        if (k0 + 16 < CC) {
            float4 xv;
            xv.x = (float)((swA >> (shA + 0)) & 1u);
            xv.y = (float)((swA >> (shA + 1)) & 1u);
            xv.z = (float)((swA >> (shA + 2)) & 1u);
            xv.w = (float)((swA >> (shA + 3)) & 1u);
            *(float4*)&Xs[nxt][kkA][4 * colA] = xv;
            xv.x = (float)((swB >> (shA + 0)) & 1u);
            xv.y = (float)((swB >> (shA + 1)) & 1u);
            xv.z = (float)((swB >> (shA + 2)) & 1u);
            xv.w = (float)((swB >> (shA + 3)) & 1u);
            *(float4*)&Xs[nxt][8 + kkA][4 * colA] = xv;
            Ws_s[nxt][4 * wkw + 0][wr] = wv4.x;
            Ws_s[nxt][4 * wkw + 1][wr] = wv4.y;
            Ws_s[nxt][4 * wkw + 2][wr] = wv4.z;
            Ws_s[nxt][4 * wkw + 3][wr] = wv4.w;
            __syncthreads();
            cur = nxt;
        }
    }

    float* ob = out + (size_t)b * CC * NN;
#pragma unroll
    for (int i = 0; i < 4; ++i) {
        int c = c0 + 4 * ty + i;
        float4 lo, hi;
        lo.x = acc[i][0] * inv_c[i] + add_c[i];
        lo.y = acc[i][1] * inv_c[i] + add_c[i];
        lo.z = acc[i][2] * inv_c[i] + add_c[i];
        lo.w = acc[i][3] * inv_c[i] + add_c[i];
        hi.x = acc[i][4] * inv_c[i] + add_c[i];
        hi.y = acc[i][5] * inv_c[i] + add_c[i];
        hi.z = acc[i][6] * inv_c[i] + add_c[i];
        hi.w = acc[i][7] * inv_c[i] + add_c[i];
        *(float4*)&ob[(size_t)c * NN + n0 + 4 * tx] = lo;
        *(float4*)&ob[(size_t)c * NN + n0 + 64 + 4 * tx] = hi;
    }
}

// ---------------------------------------------------------------------------
extern "C" void kernel_launch(void* const* d_in, const int* in_sizes, int n_in,
                              void* d_out, int out_size, void* d_ws, size_t ws_size,
                              hipStream_t stream) {
    const float* x     = (const float*)d_in[0];
    const float* wq    = (const float*)d_in[1];
    const float* wk    = (const float*)d_in[2];
    const float* wv    = (const float*)d_in[3];
    const float* wproj = (const float*)d_in[4];
    const float* bng   = (const float*)d_in[5];
    const float* bnb   = (const float*)d_in[6];
    const float* bnm   = (const float*)d_in[7];
    const float* bnv   = (const float*)d_in[8];

    const size_t PK = (size_t)BB * CC * NW;            // 2 MiB each
    uint32_t* qp  = (uint32_t*)d_ws;
    uint32_t* kp  = qp + PK;
    uint32_t* vp  = kp + PK;
    uint32_t* s3p = vp + PK;                           // total 8 MiB

    dim3 gconv(NN / 128, CC / 64, 3 * BE);             // z = w*16 + be
    conv_bn_lif_kernel<<<gconv, 256, 0, stream>>>(x, wq, wk, wv, bng, bnb, bnm, bnv,
                                                  qp, kp, vp);

    dim3 gattn(4, NH, BE);
    attn_lif_kernel<<<gattn, 256, 0, stream>>>(qp, kp, vp, s3p);

    dim3 gproj(NN / 128, CC / 64, BB);
    proj_kernel<<<gproj, 256, 0, stream>>>(s3p, wproj, bng, bnb, bnm, bnv, (float*)d_out);
}

// Round 5
// 813.022 us; speedup vs baseline: 1.9847x; 1.9847x over previous
//
#include <hip/hip_runtime.h>
#include <hip/hip_bf16.h>
#include <stdint.h>

// Problem constants
#define TT 4
#define BE 16
#define BB 64          // TT * BE
#define CC 512
#define NN 512
#define NH 8
#define GD 64          // CC / NH
#define NW 16          // NN/32 packed words per (b,c) row
#define TAU 0.5f
#define THRESH 1.0f
#define SCALE 0.125f
#define EPS 1e-5f

typedef _Float16 half8 __attribute__((ext_vector_type(8)));
typedef _Float16 half4 __attribute__((ext_vector_type(4)));
typedef float    f32x4 __attribute__((ext_vector_type(4)));

// Direct global->LDS DMA, 16B per lane: lane l writes base + l*16.
#define GLL16(g, l)                                                        \
    __builtin_amdgcn_global_load_lds(                                      \
        (const __attribute__((address_space(1))) void*)(g),                \
        (__attribute__((address_space(3))) void*)(l), 16, 0, 0)

// ---------------------------------------------------------------------------
// split_w: Wq/Wk/Wv fp32 [C][K] -> Wh/Wl fp16 pieces [3][C][K].
// x = (fp16)x + (fp16)residual: residual after 2 pieces <= 2^-24|x|.
// ---------------------------------------------------------------------------
__global__ __launch_bounds__(256) void split_w_kernel(
    const float* __restrict__ wq, const float* __restrict__ wk,
    const float* __restrict__ wv,
    _Float16* __restrict__ Wh, _Float16* __restrict__ Wl)
{
    const int gid = blockIdx.x * 256 + threadIdx.x;      // 196608 threads
    const size_t e0 = (size_t)gid * 4;
    const int mat = (int)(e0 >> 18);                     // 262144 per matrix
    const size_t off = e0 & 262143;
    const float* src = (mat == 0) ? wq : (mat == 1) ? wk : wv;
    float4 v = *(const float4*)&src[off];
    half4 h, l;
    h[0] = (_Float16)v.x; l[0] = (_Float16)(v.x - (float)h[0]);
    h[1] = (_Float16)v.y; l[1] = (_Float16)(v.y - (float)h[1]);
    h[2] = (_Float16)v.z; l[2] = (_Float16)(v.z - (float)h[2]);
    h[3] = (_Float16)v.w; l[3] = (_Float16)(v.w - (float)h[3]);
    *(half4*)&Wh[e0] = h;
    *(half4*)&Wl[e0] = l;
}

// ---------------------------------------------------------------------------
// split_xt: x fp32 [b][k=c_in][n] -> XTh/XTl fp16 TRANSPOSED [b][n][k].
// Pre-transposing makes the GEMM B-fragment a k-contiguous ds_read_b128,
// identical addressing to the A-fragment (no in-kernel transpose needed).
// 64x64 tile via padded LDS.
// ---------------------------------------------------------------------------
__global__ __launch_bounds__(256) void split_xt_kernel(
    const float* __restrict__ x,
    _Float16* __restrict__ XTh, _Float16* __restrict__ XTl)
{
    __shared__ float Ls[64][68];     // pad 68: float4-aligned rows, spread banks
    const int tid = threadIdx.x;
    const int b  = blockIdx.z;
    const int k0 = blockIdx.y * 64;
    const int n0 = blockIdx.x * 64;
    const float* xb = x + ((size_t)b * CC + k0) * NN + n0;

    const int kr = tid >> 4;        // 0..15
    const int f4 = tid & 15;        // float4 within row
#pragma unroll
    for (int i = 0; i < 4; ++i) {
        float4 v = *(const float4*)&xb[(size_t)(kr + 16 * i) * NN + f4 * 4];
        *(float4*)&Ls[kr + 16 * i][f4 * 4] = v;
    }
    __syncthreads();

    const int nr = tid >> 2;        // 0..63 output row (n)
    const int ks = tid & 3;         // k segment of 16
    half8 h0, h1, l0, l1;
#pragma unroll
    for (int j = 0; j < 8; ++j) {
        float v = Ls[ks * 16 + j][nr];
        _Float16 h = (_Float16)v;
        h0[j] = h; l0[j] = (_Float16)(v - (float)h);
    }
#pragma unroll
    for (int j = 0; j < 8; ++j) {
        float v = Ls[ks * 16 + 8 + j][nr];
        _Float16 h = (_Float16)v;
        h1[j] = h; l1[j] = (_Float16)(v - (float)h);
    }
    const size_t o = ((size_t)b * NN + n0 + nr) * CC + k0 + ks * 16;
    *(half8*)&XTh[o] = h0; *(half8*)&XTh[o + 8] = h1;
    *(half8*)&XTl[o] = l0; *(half8*)&XTl[o + 8] = l1;
}

// ---------------------------------------------------------------------------
// Kernel 1 v6: conv+BN+LIF via fp16-split MFMA (3 products: hh, hl, lh).
// Block: 256 thr = 4 waves (wr=wid>>1, wc=wid&1), tile 128c x 64n,
// wave sub-tile 64c x 32n = acc[4][2] f32x4 (32) + LIF mem[4][2] (32).
// K-loop: BK=32, v1's PROVEN 2-barrier single-buffer schedule (every
// pipelining variant v3-v5 blew the 128-VGPR cliff; don't).
// LDS: flat T = Ah[16ch]|Al|Bh[4ch]|Bl slots of 512 halfs, staged by 6
// wave-glls/wave/step, linear lane order. Frag reads are k-contiguous
// ds_read_b128 at the b128 bank floor (8 touches/bank - no swizzle needed).
// MFMA 16x16x32_f16, C/D layout: col=lane&15, row=(lane>>4)*4+reg (m89).
// Epilogue: BN + LIF -> bit = (lane&15) | nf*16, OR-shfl over 16 lanes.
// ---------------------------------------------------------------------------
__global__ __launch_bounds__(256) void conv_mfma_kernel(
    const _Float16* __restrict__ Wh,   // [3][CC][CC]
    const _Float16* __restrict__ Wl,
    const _Float16* __restrict__ XTh,  // [BB][NN][CC] (n-major, k-contig)
    const _Float16* __restrict__ XTl,
    const float* __restrict__ bn_g,    // [4][CC]
    const float* __restrict__ bn_b,
    const float* __restrict__ bn_m,
    const float* __restrict__ bn_v,
    uint32_t* __restrict__ qp,
    uint32_t* __restrict__ kp,
    uint32_t* __restrict__ vp)
{
    __shared__ _Float16 T[12288];   // 24 slots * 512 halfs = 24.5 KB

    const int tid = threadIdx.x;
    const int lane = tid & 63;
    const int wid  = tid >> 6;        // 0..3
    const int wr = wid >> 1;          // c-half of block tile
    const int wc = wid & 1;           // n-half
    const int lr = lane & 15;         // frag row/col select
    const int g  = lane >> 4;         // k-group (8 k's each)

    const int n0 = blockIdx.x * 64;
    const int c0 = blockIdx.y * 128;
    const int z  = blockIdx.z;        // w*16 + be
    const int be = z & (BE - 1);
    const int wmat = z >> 4;          // 0=q 1=k 2=v

    uint32_t* outp = (wmat == 0) ? qp : (wmat == 1) ? kp : vp;

    // staging lane geometry: slot = 16 rows x 64B; lane -> (row l>>2, 16B l&3)
    const int rA = lane >> 2;
    const int cB = (lane & 3) * 8;    // k-offset in halfs

    const _Float16* pWh = Wh + (size_t)wmat * CC * CC + (size_t)(c0 + rA) * CC + cB;
    const _Float16* pWl = Wl + (size_t)wmat * CC * CC + (size_t)(c0 + rA) * CC + cB;

    // frag LDS byte-offset bases (halfs)
    const int aoff = (wr * 64 + lr) * 32 + g * 8;            // Ah + mf*512
    const int boff = 8192 + (wc * 32 + lr) * 32 + g * 8;     // Bh + nf*512

    f32x4 mem[4][2];
#pragma unroll
    for (int mf = 0; mf < 4; ++mf)
#pragma unroll
        for (int nf = 0; nf < 2; ++nf) mem[mf][nf] = (f32x4)0.0f;

    for (int t = 0; t < TT; ++t) {
        const int b = t * BE + be;
        const _Float16* pXh = XTh + ((size_t)b * NN + n0 + rA) * CC + cB;
        const _Float16* pXl = XTl + ((size_t)b * NN + n0 + rA) * CC + cB;

        f32x4 acc[4][2];
#pragma unroll
        for (int mf = 0; mf < 4; ++mf)
#pragma unroll
            for (int nf = 0; nf < 2; ++nf) acc[mf][nf] = (f32x4)0.0f;

        for (int k0 = 0; k0 < CC; k0 += 32) {
            __syncthreads();   // all frag readers of T done
            // 6 wave-glls: Ah chunks {wid, wid+4}, Al same, Bh/Bl chunk wid
            GLL16(pWh + (size_t)(wid * 16) * CC + k0,      T + (wid +  0) * 512);
            GLL16(pWh + (size_t)((wid + 4) * 16) * CC + k0, T + (wid + 4) * 512);
            GLL16(pWl + (size_t)(wid * 16) * CC + k0,      T + (wid +  8) * 512);
            GLL16(pWl + (size_t)((wid + 4) * 16) * CC + k0, T + (wid + 12) * 512);
            GLL16(pXh + (size_t)(wid * 16) * CC + k0,      T + (wid + 16) * 512);
            GLL16(pXl + (size_t)(wid * 16) * CC + k0,      T + (wid + 20) * 512);
            __syncthreads();   // vmcnt drained: tile ready

            half8 ah[4], al[4], bh[2], bl[2];
#pragma unroll
            for (int mf = 0; mf < 4; ++mf) {
                ah[mf] = *(const half8*)&T[aoff + mf * 512];
                al[mf] = *(const half8*)&T[4096 + aoff + mf * 512];
            }
#pragma unroll
            for (int nf = 0; nf < 2; ++nf) {
                bh[nf] = *(const half8*)&T[boff + nf * 512];
                bl[nf] = *(const half8*)&T[2048 + boff + nf * 512];
            }
#pragma unroll
            for (int mf = 0; mf < 4; ++mf)
#pragma unroll
                for (int nf = 0; nf < 2; ++nf) {
                    acc[mf][nf] = __builtin_amdgcn_mfma_f32_16x16x32_f16(
                        ah[mf], bh[nf], acc[mf][nf], 0, 0, 0);
                    acc[mf][nf] = __builtin_amdgcn_mfma_f32_16x16x32_f16(
                        ah[mf], bl[nf], acc[mf][nf], 0, 0, 0);
                    acc[mf][nf] = __builtin_amdgcn_mfma_f32_16x16x32_f16(
                        al[mf], bh[nf], acc[mf][nf], 0, 0, 0);
                }
        }

        // epilogue: BN + LIF -> pack. lane holds col n = n0+wc*32+nf*16+lr,
        // row c = c0+wr*64+mf*16+4g+r. word bit = nf*16+lr.
        const int nword = blockIdx.x * 2 + wc;
#pragma unroll
        for (int mf = 0; mf < 4; ++mf) {
#pragma unroll
            for (int r = 0; r < 4; ++r) {
                const int c = c0 + wr * 64 + mf * 16 + 4 * g + r;
                const float gg = bn_g[wmat * CC + c];
                const float bb = bn_b[wmat * CC + c];
                const float mm = bn_m[wmat * CC + c];
                const float vv = bn_v[wmat * CC + c];
                const float inv = gg / sqrtf(vv + EPS);
                const float add = bb - mm * inv;

                float y0 = acc[mf][0][r] * inv + add;
                float m0 = mem[mf][0][r] * TAU + y0;
                bool s0 = m0 > THRESH;
                mem[mf][0][r] = s0 ? 0.0f : m0;

                float y1 = acc[mf][1][r] * inv + add;
                float m1 = mem[mf][1][r] * TAU + y1;
                bool s1 = m1 > THRESH;
                mem[mf][1][r] = s1 ? 0.0f : m1;

                uint32_t wbits = ((s0 ? 1u : 0u) << lr) | ((s1 ? 1u : 0u) << (16 + lr));
                wbits |= (uint32_t)__shfl_xor((int)wbits, 1);
                wbits |= (uint32_t)__shfl_xor((int)wbits, 2);
                wbits |= (uint32_t)__shfl_xor((int)wbits, 4);
                wbits |= (uint32_t)__shfl_xor((int)wbits, 8);
                if (lr == 0) {
                    outp[(size_t)(b * CC + c) * NW + nword] = wbits;
                }
            }
        }
    }
}

// ---------------------------------------------------------------------------
// Kernel 2: fused attention + LIF3 on packed spikes (unchanged, verified).
// ---------------------------------------------------------------------------
__global__ __launch_bounds__(256) void attn_lif_kernel(
    const uint32_t* __restrict__ qp,
    const uint32_t* __restrict__ kp,
    const uint32_t* __restrict__ vp,
    uint32_t* __restrict__ s3p)
{
    __shared__ uint32_t kL[64][NW + 1];
    __shared__ uint32_t vL[64][NW + 1];
    __shared__ float    Msh[64][64 + 1];
    __shared__ uint32_t qL[64][5];

    const int tid = threadIdx.x;
    const int nchunk = blockIdx.x;
    const int h = blockIdx.y;
    const int be = blockIdx.z;
    const int d_own = tid >> 2;
    const int nw_own = tid & 3;

    float mem[32];
#pragma unroll
    for (int i = 0; i < 32; ++i) mem[i] = 0.0f;

    for (int t = 0; t < TT; ++t) {
        const int b = t * BE + be;
        const size_t base_row = (size_t)(b * CC + h * GD);

        for (int i = tid; i < 64 * NW; i += 256) {
            int r = i >> 4;
            int w = i & (NW - 1);
            kL[r][w] = kp[(base_row + r) * NW + w];
            vL[r][w] = vp[(base_row + r) * NW + w];
        }
        {
            int r = tid >> 2;
            int w = tid & 3;
            qL[r][w] = qp[(base_row + r) * NW + nchunk * 4 + w];
        }
        __syncthreads();

        for (int e = tid; e < 64 * 64; e += 256) {
            int d = e >> 6;
            int dp = e & 63;
            int s = 0;
#pragma unroll
            for (int w = 0; w < NW; ++w) s += __popc(vL[d][w] & kL[dp][w]);
            Msh[d][dp] = (float)s;
        }
        __syncthreads();

        float acc[32];
#pragma unroll
        for (int i = 0; i < 32; ++i) acc[i] = 0.0f;

        for (int dp = 0; dp < 64; ++dp) {
            float Mv = Msh[d_own][dp];
            uint32_t w = qL[dp][nw_own];
#pragma unroll
            for (int b2 = 0; b2 < 32; ++b2) {
                acc[b2] += ((w >> b2) & 1u) ? Mv : 0.0f;
            }
        }

        uint32_t sw = 0;
#pragma unroll
        for (int b2 = 0; b2 < 32; ++b2) {
            float m2 = mem[b2] * TAU + SCALE * acc[b2];
            bool s = m2 > THRESH;
            sw |= (s ? 1u : 0u) << b2;
            mem[b2] = s ? 0.0f : m2;
        }
        s3p[(base_row + d_own) * NW + nchunk * 4 + nw_own] = sw;
        __syncthreads();
    }
}

// ---------------------------------------------------------------------------
// Kernel 3 (round-2 improved version, unchanged): projection conv + BN on
// packed spikes -> fp32 output. Double-buffered, 1 barrier/k-step.
// ---------------------------------------------------------------------------
__global__ __launch_bounds__(256) void proj_kernel(
    const uint32_t* __restrict__ s3p,          // [BB*CC, NW] packed
    const float* __restrict__ W,               // [CC, CC]
    const float* __restrict__ bn_g,
    const float* __restrict__ bn_b,
    const float* __restrict__ bn_m,
    const float* __restrict__ bn_v,
    float* __restrict__ out)                   // [BB, CC, NN]
{
    __shared__ float Xs[2][16][132];
    __shared__ float Ws_s[2][16][68];

    const int tid = threadIdx.x;
    const int tx = tid & 15;
    const int ty = tid >> 4;
    const int n0 = blockIdx.x * 128;
    const int c0 = blockIdx.y * 64;
    const int b = blockIdx.z;

    float inv_c[4], add_c[4];
#pragma unroll
    for (int i = 0; i < 4; ++i) {
        int c = c0 + 4 * ty + i;
        float g = bn_g[3 * CC + c];
        float bt = bn_b[3 * CC + c];
        float m = bn_m[3 * CC + c];
        float v = bn_v[3 * CC + c];
        float inv = g / sqrtf(v + EPS);
        inv_c[i] = inv;
        add_c[i] = bt - m * inv;
    }

    const int wr  = tid >> 2;
    const int wkw = tid & 3;
    const int kkA = tid >> 5;
    const int colA = tid & 31;
    const int shA = 4 * (colA & 7);

    const float* Wrow = W + (size_t)(c0 + wr) * CC + 4 * wkw;
    const uint32_t* sp = s3p + (size_t)(b * CC) * NW + (n0 >> 5) + (colA >> 3);

    float acc[4][8];
#pragma unroll
    for (int i = 0; i < 4; ++i)
#pragma unroll
        for (int j = 0; j < 8; ++j) acc[i][j] = 0.0f;

    {
        uint32_t swA = sp[(size_t)kkA * NW];
        uint32_t swB = sp[(size_t)(8 + kkA) * NW];
        float4 wv4 = *(const float4*)&Wrow[0];
        float4 xv;
        xv.x = (float)((swA >> (shA + 0)) & 1u);
        xv.y = (float)((swA >> (shA + 1)) & 1u);
        xv.z = (float)((swA >> (shA + 2)) & 1u);
        xv.w = (float)((swA >> (shA + 3)) & 1u);
        *(float4*)&Xs[0][kkA][4 * colA] = xv;
        xv.x = (float)((swB >> (shA + 0)) & 1u);
        xv.y = (float)((swB >> (shA + 1)) & 1u);
        xv.z = (float)((swB >> (shA + 2)) & 1u);
        xv.w = (float)((swB >> (shA + 3)) & 1u);
        *(float4*)&Xs[0][8 + kkA][4 * colA] = xv;
        Ws_s[0][4 * wkw + 0][wr] = wv4.x;
        Ws_s[0][4 * wkw + 1][wr] = wv4.y;
        Ws_s[0][4 * wkw + 2][wr] = wv4.z;
        Ws_s[0][4 * wkw + 3][wr] = wv4.w;
    }
    __syncthreads();

    int cur = 0;
    for (int k0 = 0; k0 < CC; k0 += 16) {
        const int nxt = cur ^ 1;
        uint32_t swA, swB;
        float4 wv4;
        if (k0 + 16 < CC) {
            swA = sp[(size_t)(k0 + 16 + kkA) * NW];
            swB = sp[(size_t)(k0 + 24 + kkA) * NW];
            wv4 = *(const float4*)&Wrow[k0 + 16];
        }

#pragma unroll
        for (int kk = 0; kk < 16; ++kk) {
            float4 av  = *(float4*)&Ws_s[cur][kk][4 * ty];
            float4 xlo = *(float4*)&Xs[cur][kk][4 * tx];
            float4 xhi = *(float4*)&Xs[cur][kk][64 + 4 * tx];
            const float a[4]  = {av.x, av.y, av.z, av.w};
            const float xl[4] = {xlo.x, xlo.y, xlo.z, xlo.w};
            const float xh[4] = {xhi.x, xhi.y, xhi.z, xhi.w};
#pragma unroll
            for (int i = 0; i < 4; ++i) {
#pragma unroll
                for (int j = 0; j < 4; ++j) {
                    acc[i][j]     += a[i] * xl[j];
                    acc[i][4 + j] += a[i] * xh[j];
                }
            }
        }

        if (k0 + 16 < CC) {
            float4 xv;
            xv.x = (float)((swA >> (shA + 0)) & 1u);
            xv.y = (float)((swA >> (shA + 1)) & 1u);
            xv.z = (float)((swA >> (shA + 2)) & 1u);
            xv.w = (float)((swA >> (shA + 3)) & 1u);
            *(float4*)&Xs[nxt][kkA][4 * colA] = xv;
            xv.x = (float)((swB >> (shA + 0)) & 1u);
            xv.y = (float)((swB >> (shA + 1)) & 1u);
            xv.z = (float)((swB >> (shA + 2)) & 1u);
            xv.w = (float)((swB >> (shA + 3)) & 1u);
            *(float4*)&Xs[nxt][8 + kkA][4 * colA] = xv;
            Ws_s[nxt][4 * wkw + 0][wr] = wv4.x;
            Ws_s[nxt][4 * wkw + 1][wr] = wv4.y;
            Ws_s[nxt][4 * wkw + 2][wr] = wv4.z;
            Ws_s[nxt][4 * wkw + 3][wr] = wv4.w;
            __syncthreads();
            cur = nxt;
        }
    }

    float* ob = out + (size_t)b * CC * NN;
#pragma unroll
    for (int i = 0; i < 4; ++i) {
        int c = c0 + 4 * ty + i;
        float4 lo, hi;
        lo.x = acc[i][0] * inv_c[i] + add_c[i];
        lo.y = acc[i][1] * inv_c[i] + add_c[i];
        lo.z = acc[i][2] * inv_c[i] + add_c[i];
        lo.w = acc[i][3] * inv_c[i] + add_c[i];
        hi.x = acc[i][4] * inv_c[i] + add_c[i];
        hi.y = acc[i][5] * inv_c[i] + add_c[i];
        hi.z = acc[i][6] * inv_c[i] + add_c[i];
        hi.w = acc[i][7] * inv_c[i] + add_c[i];
        *(float4*)&ob[(size_t)c * NN + n0 + 4 * tx] = lo;
        *(float4*)&ob[(size_t)c * NN + n0 + 64 + 4 * tx] = hi;
    }
}

// ---------------------------------------------------------------------------
extern "C" void kernel_launch(void* const* d_in, const int* in_sizes, int n_in,
                              void* d_out, int out_size, void* d_ws, size_t ws_size,
                              hipStream_t stream) {
    const float* x     = (const float*)d_in[0];
    const float* wq    = (const float*)d_in[1];
    const float* wk    = (const float*)d_in[2];
    const float* wv    = (const float*)d_in[3];
    const float* wproj = (const float*)d_in[4];
    const float* bng   = (const float*)d_in[5];
    const float* bnb   = (const float*)d_in[6];
    const float* bnm   = (const float*)d_in[7];
    const float* bnv   = (const float*)d_in[8];

    // ws layout (bytes):
    //  [0,8M): packed spikes qp/kp/vp/s3p (2 MiB each)
    //  [8M): Wh [3][512][512] fp16 (1.5M), [10M): Wl
    //  [12M): XTh [64][512][512] fp16 (32M), [44M): XTl   -> ~76 MiB total
    uint8_t* ws = (uint8_t*)d_ws;
    const size_t PK = (size_t)BB * CC * NW;
    uint32_t* qp  = (uint32_t*)ws;
    uint32_t* kp  = qp + PK;
    uint32_t* vp  = kp + PK;
    uint32_t* s3p = vp + PK;
    _Float16* Wh  = (_Float16*)(ws + ((size_t)8  << 20));
    _Float16* Wl  = (_Float16*)(ws + ((size_t)10 << 20));
    _Float16* XTh = (_Float16*)(ws + ((size_t)12 << 20));
    _Float16* XTl = (_Float16*)(ws + ((size_t)44 << 20));

    split_w_kernel<<<768, 256, 0, stream>>>(wq, wk, wv, Wh, Wl);
    split_xt_kernel<<<dim3(8, 8, BB), 256, 0, stream>>>(x, XTh, XTl);

    dim3 gconv(NN / 64, CC / 128, 3 * BE);             // z = w*16 + be
    conv_mfma_kernel<<<gconv, 256, 0, stream>>>(Wh, Wl, XTh, XTl,
                                                bng, bnb, bnm, bnv, qp, kp, vp);

    dim3 gattn(4, NH, BE);
    attn_lif_kernel<<<gattn, 256, 0, stream>>>(qp, kp, vp, s3p);

    dim3 gproj(NN / 128, CC / 64, BB);
    proj_kernel<<<gproj, 256, 0, stream>>>(s3p, wproj, bng, bnb, bnm, bnv, (float*)d_out);
}

// Round 6
// 760.005 us; speedup vs baseline: 2.1232x; 1.0698x over previous
//
#include <hip/hip_runtime.h>
#include <hip/hip_bf16.h>
#include <stdint.h>

// Problem constants
#define TT 4
#define BE 16
#define BB 64          // TT * BE
#define CC 512
#define NN 512
#define NH 8
#define GD 64          // CC / NH
#define NW 16          // NN/32 packed words per (b,c) row
#define TAU 0.5f
#define THRESH 1.0f
#define SCALE 0.125f
#define EPS 1e-5f

typedef _Float16 half8 __attribute__((ext_vector_type(8)));
typedef _Float16 half4 __attribute__((ext_vector_type(4)));
typedef float    f32x4 __attribute__((ext_vector_type(4)));

// Direct global->LDS DMA, 16B per lane: lane l writes base + l*16.
#define GLL16(g, l)                                                        \
    __builtin_amdgcn_global_load_lds(                                      \
        (const __attribute__((address_space(1))) void*)(g),                \
        (__attribute__((address_space(3))) void*)(l), 16, 0, 0)

// ---------------------------------------------------------------------------
// split_w: Wq/Wk/Wv/Wproj fp32 [C][K] -> Wh/Wl fp16 pieces [4][C][K].
// x = (fp16)x + (fp16)residual: residual after 2 pieces <= 2^-24|x|.
// ---------------------------------------------------------------------------
__global__ __launch_bounds__(256) void split_w_kernel(
    const float* __restrict__ wq, const float* __restrict__ wk,
    const float* __restrict__ wv, const float* __restrict__ wp,
    _Float16* __restrict__ Wh, _Float16* __restrict__ Wl)
{
    const int gid = blockIdx.x * 256 + threadIdx.x;      // 262144 threads
    const size_t e0 = (size_t)gid * 4;
    const int mat = (int)(e0 >> 18);                     // 262144 elems / matrix
    const size_t off = e0 & 262143;
    const float* src = (mat == 0) ? wq : (mat == 1) ? wk : (mat == 2) ? wv : wp;
    float4 v = *(const float4*)&src[off];
    half4 h, l;
    h[0] = (_Float16)v.x; l[0] = (_Float16)(v.x - (float)h[0]);
    h[1] = (_Float16)v.y; l[1] = (_Float16)(v.y - (float)h[1]);
    h[2] = (_Float16)v.z; l[2] = (_Float16)(v.z - (float)h[2]);
    h[3] = (_Float16)v.w; l[3] = (_Float16)(v.w - (float)h[3]);
    *(half4*)&Wh[e0] = h;
    *(half4*)&Wl[e0] = l;
}

// ---------------------------------------------------------------------------
// split_xt: x fp32 [b][k][n] -> XTh/XTl fp16 TRANSPOSED [b][n][k] (unchanged).
// ---------------------------------------------------------------------------
__global__ __launch_bounds__(256) void split_xt_kernel(
    const float* __restrict__ x,
    _Float16* __restrict__ XTh, _Float16* __restrict__ XTl)
{
    __shared__ float Ls[64][68];
    const int tid = threadIdx.x;
    const int b  = blockIdx.z;
    const int k0 = blockIdx.y * 64;
    const int n0 = blockIdx.x * 64;
    const float* xb = x + ((size_t)b * CC + k0) * NN + n0;

    const int kr = tid >> 4;
    const int f4 = tid & 15;
#pragma unroll
    for (int i = 0; i < 4; ++i) {
        float4 v = *(const float4*)&xb[(size_t)(kr + 16 * i) * NN + f4 * 4];
        *(float4*)&Ls[kr + 16 * i][f4 * 4] = v;
    }
    __syncthreads();

    const int nr = tid >> 2;
    const int ks = tid & 3;
    half8 h0, h1, l0, l1;
#pragma unroll
    for (int j = 0; j < 8; ++j) {
        float v = Ls[ks * 16 + j][nr];
        _Float16 h = (_Float16)v;
        h0[j] = h; l0[j] = (_Float16)(v - (float)h);
    }
#pragma unroll
    for (int j = 0; j < 8; ++j) {
        float v = Ls[ks * 16 + 8 + j][nr];
        _Float16 h = (_Float16)v;
        h1[j] = h; l1[j] = (_Float16)(v - (float)h);
    }
    const size_t o = ((size_t)b * NN + n0 + nr) * CC + k0 + ks * 16;
    *(half8*)&XTh[o] = h0; *(half8*)&XTh[o + 8] = h1;
    *(half8*)&XTl[o] = l0; *(half8*)&XTl[o + 8] = l1;
}

// ---------------------------------------------------------------------------
// Kernel 1 v7: conv+BN+LIF via fp16-split MFMA.
// vs v6 (383us, MfmaUtil 16.5%, 1.9e7 bank conflicts, ~1 block/CU):
//  (a) FRAGMENT-ORDER staging: gll source mapped (row=lane&15, q=lane>>4) so
//      the linear LDS dest (lane*16B) IS fragment order; frag ds_read_b128 is
//      slot + lane*16B -> 2-way max (free). Data per lane identical to v6's
//      verified mapping -> numerics unchanged.
//  (b) Double-buffered T[2], static two-phase loop (literal T[0]/T[1], no
//      dynamic index - the v3/v4 VGPR killer), glls for tile k+1 issued
//      BEFORE compute of tile k; one barrier per tile: gll latency hidden
//      under ~500cyc of MFMA+LDS even at 1 resident block.
// ---------------------------------------------------------------------------
__global__ __launch_bounds__(256) void conv_mfma_kernel(
    const _Float16* __restrict__ Wh,   // [4][CC][CC]
    const _Float16* __restrict__ Wl,
    const _Float16* __restrict__ XTh,  // [BB][NN][CC]
    const _Float16* __restrict__ XTl,
    const float* __restrict__ bn_g,    // [4][CC]
    const float* __restrict__ bn_b,
    const float* __restrict__ bn_m,
    const float* __restrict__ bn_v,
    uint32_t* __restrict__ qp,
    uint32_t* __restrict__ kp,
    uint32_t* __restrict__ vp)
{
    __shared__ _Float16 T[2][12288];   // 2 x 24 slots x 512 halfs = 48 KB

    const int tid = threadIdx.x;
    const int lane = tid & 63;
    const int wid  = tid >> 6;        // 0..3
    const int wr = wid >> 1;          // c-half of block tile
    const int wc = wid & 1;           // n-half
    const int lr = lane & 15;
    const int g  = lane >> 4;
    const int lane8 = lane * 8;       // frag read offset in halfs

    const int n0 = blockIdx.x * 64;
    const int c0 = blockIdx.y * 128;
    const int z  = blockIdx.z;        // w*16 + be
    const int be = z & (BE - 1);
    const int wmat = z >> 4;

    uint32_t* outp = (wmat == 0) ? qp : (wmat == 1) ? kp : vp;

    // fragment-order staging source: lane -> (row lane&15, k-quarter lane>>4)
    const _Float16* pWh = Wh + (size_t)wmat * CC * CC + (size_t)(c0 + lr) * CC + g * 8;
    const _Float16* pWl = Wl + (size_t)wmat * CC * CC + (size_t)(c0 + lr) * CC + g * 8;

#define CSTAGE(Tb, k0) do {                                                   \
        GLL16(pWh + (size_t)(wid * 16) * CC + (k0),       &(Tb)[(wid +  0) * 512]); \
        GLL16(pWh + (size_t)((wid + 4) * 16) * CC + (k0), &(Tb)[(wid +  4) * 512]); \
        GLL16(pWl + (size_t)(wid * 16) * CC + (k0),       &(Tb)[(wid +  8) * 512]); \
        GLL16(pWl + (size_t)((wid + 4) * 16) * CC + (k0), &(Tb)[(wid + 12) * 512]); \
        GLL16(pXh + (size_t)(wid * 16) * CC + (k0),       &(Tb)[(wid + 16) * 512]); \
        GLL16(pXl + (size_t)(wid * 16) * CC + (k0),       &(Tb)[(wid + 20) * 512]); \
    } while (0)

#define CCOMP(Tb) do {                                                        \
        half8 ah[4], al[4], bh[2], bl[2];                                     \
        _Pragma("unroll")                                                     \
        for (int mf = 0; mf < 4; ++mf) {                                      \
            ah[mf] = *(const half8*)&(Tb)[(wr * 4 + mf) * 512 + lane8];       \
            al[mf] = *(const half8*)&(Tb)[(8 + wr * 4 + mf) * 512 + lane8];   \
        }                                                                     \
        _Pragma("unroll")                                                     \
        for (int nf = 0; nf < 2; ++nf) {                                      \
            bh[nf] = *(const half8*)&(Tb)[(16 + wc * 2 + nf) * 512 + lane8];  \
            bl[nf] = *(const half8*)&(Tb)[(20 + wc * 2 + nf) * 512 + lane8];  \
        }                                                                     \
        _Pragma("unroll")                                                     \
        for (int mf = 0; mf < 4; ++mf)                                        \
        _Pragma("unroll")                                                     \
            for (int nf = 0; nf < 2; ++nf) {                                  \
                acc[mf][nf] = __builtin_amdgcn_mfma_f32_16x16x32_f16(         \
                    ah[mf], bh[nf], acc[mf][nf], 0, 0, 0);                    \
                acc[mf][nf] = __builtin_amdgcn_mfma_f32_16x16x32_f16(         \
                    ah[mf], bl[nf], acc[mf][nf], 0, 0, 0);                    \
                acc[mf][nf] = __builtin_amdgcn_mfma_f32_16x16x32_f16(         \
                    al[mf], bh[nf], acc[mf][nf], 0, 0, 0);                    \
            }                                                                 \
    } while (0)

    f32x4 mem[4][2];
#pragma unroll
    for (int mf = 0; mf < 4; ++mf)
#pragma unroll
        for (int nf = 0; nf < 2; ++nf) mem[mf][nf] = (f32x4)0.0f;

    for (int t = 0; t < TT; ++t) {
        const int b = t * BE + be;
        const _Float16* pXh = XTh + ((size_t)b * NN + n0 + lr) * CC + g * 8;
        const _Float16* pXl = XTl + ((size_t)b * NN + n0 + lr) * CC + g * 8;

        f32x4 acc[4][2];
#pragma unroll
        for (int mf = 0; mf < 4; ++mf)
#pragma unroll
            for (int nf = 0; nf < 2; ++nf) acc[mf][nf] = (f32x4)0.0f;

        CSTAGE(T[0], 0);
        __syncthreads();              // buf0 ready (drains glls)

#pragma unroll 1
        for (int it = 0; it < 8; ++it) {
            CSTAGE(T[1], it * 64 + 32);   // issue next tile before compute
            CCOMP(T[0]);
            __syncthreads();              // drains T1 glls; seals T0 reads
            if (it < 7) CSTAGE(T[0], it * 64 + 64);
            CCOMP(T[1]);
            __syncthreads();              // drains T0 glls; seals T1 reads
        }

        // epilogue: BN + LIF -> pack. lane: col n=n0+wc*32+nf*16+lr,
        // row c=c0+wr*64+mf*16+4g+r, word bit = nf*16+lr.
        const int nword = blockIdx.x * 2 + wc;
#pragma unroll
        for (int mf = 0; mf < 4; ++mf) {
#pragma unroll
            for (int r = 0; r < 4; ++r) {
                const int c = c0 + wr * 64 + mf * 16 + 4 * g + r;
                const float gg = bn_g[wmat * CC + c];
                const float bb = bn_b[wmat * CC + c];
                const float mm = bn_m[wmat * CC + c];
                const float vv = bn_v[wmat * CC + c];
                const float inv = gg / sqrtf(vv + EPS);
                const float add = bb - mm * inv;

                float y0 = acc[mf][0][r] * inv + add;
                float m0 = mem[mf][0][r] * TAU + y0;
                bool s0 = m0 > THRESH;
                mem[mf][0][r] = s0 ? 0.0f : m0;

                float y1 = acc[mf][1][r] * inv + add;
                float m1 = mem[mf][1][r] * TAU + y1;
                bool s1 = m1 > THRESH;
                mem[mf][1][r] = s1 ? 0.0f : m1;

                uint32_t wbits = ((s0 ? 1u : 0u) << lr) | ((s1 ? 1u : 0u) << (16 + lr));
                wbits |= (uint32_t)__shfl_xor((int)wbits, 1);
                wbits |= (uint32_t)__shfl_xor((int)wbits, 2);
                wbits |= (uint32_t)__shfl_xor((int)wbits, 4);
                wbits |= (uint32_t)__shfl_xor((int)wbits, 8);
                if (lr == 0) {
                    outp[(size_t)(b * CC + c) * NW + nword] = wbits;
                }
            }
        }
    }
#undef CSTAGE
#undef CCOMP
}

// ---------------------------------------------------------------------------
// Kernel 2: fused attention + LIF3 on packed spikes (unchanged, verified).
// ---------------------------------------------------------------------------
__global__ __launch_bounds__(256) void attn_lif_kernel(
    const uint32_t* __restrict__ qp,
    const uint32_t* __restrict__ kp,
    const uint32_t* __restrict__ vp,
    uint32_t* __restrict__ s3p)
{
    __shared__ uint32_t kL[64][NW + 1];
    __shared__ uint32_t vL[64][NW + 1];
    __shared__ float    Msh[64][64 + 1];
    __shared__ uint32_t qL[64][5];

    const int tid = threadIdx.x;
    const int nchunk = blockIdx.x;
    const int h = blockIdx.y;
    const int be = blockIdx.z;
    const int d_own = tid >> 2;
    const int nw_own = tid & 3;

    float mem[32];
#pragma unroll
    for (int i = 0; i < 32; ++i) mem[i] = 0.0f;

    for (int t = 0; t < TT; ++t) {
        const int b = t * BE + be;
        const size_t base_row = (size_t)(b * CC + h * GD);

        for (int i = tid; i < 64 * NW; i += 256) {
            int r = i >> 4;
            int w = i & (NW - 1);
            kL[r][w] = kp[(base_row + r) * NW + w];
            vL[r][w] = vp[(base_row + r) * NW + w];
        }
        {
            int r = tid >> 2;
            int w = tid & 3;
            qL[r][w] = qp[(base_row + r) * NW + nchunk * 4 + w];
        }
        __syncthreads();

        for (int e = tid; e < 64 * 64; e += 256) {
            int d = e >> 6;
            int dp = e & 63;
            int s = 0;
#pragma unroll
            for (int w = 0; w < NW; ++w) s += __popc(vL[d][w] & kL[dp][w]);
            Msh[d][dp] = (float)s;
        }
        __syncthreads();

        float acc[32];
#pragma unroll
        for (int i = 0; i < 32; ++i) acc[i] = 0.0f;

        for (int dp = 0; dp < 64; ++dp) {
            float Mv = Msh[d_own][dp];
            uint32_t w = qL[dp][nw_own];
#pragma unroll
            for (int b2 = 0; b2 < 32; ++b2) {
                acc[b2] += ((w >> b2) & 1u) ? Mv : 0.0f;
            }
        }

        uint32_t sw = 0;
#pragma unroll
        for (int b2 = 0; b2 < 32; ++b2) {
            float m2 = mem[b2] * TAU + SCALE * acc[b2];
            bool s = m2 > THRESH;
            sw |= (s ? 1u : 0u) << b2;
            mem[b2] = s ? 0.0f : m2;
        }
        s3p[(base_row + d_own) * NW + nchunk * 4 + nw_own] = sw;
        __syncthreads();
    }
}

// ---------------------------------------------------------------------------
// unpack: s3p packed spikes (c-major words over n) -> XSp fp16 [b][n][k=c].
// LDS transpose: block = one b, 64 c-rows, all 512 n.
// ---------------------------------------------------------------------------
__global__ __launch_bounds__(256) void unpack_kernel(
    const uint32_t* __restrict__ s3p, _Float16* __restrict__ XSp)
{
    __shared__ uint32_t Wd[64][NW + 1];
    const int tid = threadIdx.x;
    const int c0 = blockIdx.x * 64;
    const int b  = blockIdx.y;
    const uint32_t* sp = s3p + ((size_t)b * CC + c0) * NW;

#pragma unroll
    for (int s = 0; s < 4; ++s) {
        int i = tid + s * 256;
        Wd[i >> 4][i & 15] = sp[i];
    }
    __syncthreads();

#pragma unroll
    for (int s = 0; s < 2; ++s) {
        const int n = tid + s * 256;
        const int nw = n >> 5, bit = n & 31;
        _Float16* dst = XSp + ((size_t)b * NN + n) * CC + c0;
#pragma unroll
        for (int c8 = 0; c8 < 8; ++c8) {
            half8 h;
#pragma unroll
            for (int j = 0; j < 8; ++j)
                h[j] = ((Wd[c8 * 8 + j][nw] >> bit) & 1u) ? (_Float16)1.0f
                                                          : (_Float16)0.0f;
            *(half8*)&dst[c8 * 8] = h;
        }
    }
}

// ---------------------------------------------------------------------------
// Kernel 3 v4: projection conv + BN via MFMA. Spikes are exact in fp16, so
// only 2 products (Wh*X + Wl*X). Same fragment-order staging + dbuf pipeline
// as conv v7. Grid (NN/64, CC/128, BB).
// ---------------------------------------------------------------------------
__global__ __launch_bounds__(256) void proj_mfma_kernel(
    const _Float16* __restrict__ Wh,   // [4][CC][CC], uses mat 3
    const _Float16* __restrict__ Wl,
    const _Float16* __restrict__ XSp,  // [BB][NN][CC]
    const float* __restrict__ bn_g,
    const float* __restrict__ bn_b,
    const float* __restrict__ bn_m,
    const float* __restrict__ bn_v,
    float* __restrict__ out)           // [BB][CC][NN]
{
    __shared__ _Float16 P[2][10240];   // 2 x 20 slots x 512 halfs = 40 KB

    const int tid = threadIdx.x;
    const int lane = tid & 63;
    const int wid  = tid >> 6;
    const int wr = wid >> 1;
    const int wc = wid & 1;
    const int lr = lane & 15;
    const int g  = lane >> 4;
    const int lane8 = lane * 8;

    const int n0 = blockIdx.x * 64;
    const int c0 = blockIdx.y * 128;
    const int b  = blockIdx.z;

    const _Float16* pWh = Wh + (size_t)3 * CC * CC + (size_t)(c0 + lr) * CC + g * 8;
    const _Float16* pWl = Wl + (size_t)3 * CC * CC + (size_t)(c0 + lr) * CC + g * 8;
    const _Float16* pX  = XSp + ((size_t)b * NN + n0 + lr) * CC + g * 8;

#define PSTAGE(Pb, k0) do {                                                   \
        GLL16(pWh + (size_t)(wid * 16) * CC + (k0),       &(Pb)[(wid +  0) * 512]); \
        GLL16(pWh + (size_t)((wid + 4) * 16) * CC + (k0), &(Pb)[(wid +  4) * 512]); \
        GLL16(pWl + (size_t)(wid * 16) * CC + (k0),       &(Pb)[(wid +  8) * 512]); \
        GLL16(pWl + (size_t)((wid + 4) * 16) * CC + (k0), &(Pb)[(wid + 12) * 512]); \
        GLL16(pX  + (size_t)(wid * 16) * CC + (k0),       &(Pb)[(wid + 16) * 512]); \
    } while (0)

#define PCOMP(Pb) do {                                                        \
        half8 ah[4], al[4], bh[2];                                            \
        _Pragma("unroll")                                                     \
        for (int mf = 0; mf < 4; ++mf) {                                      \
            ah[mf] = *(const half8*)&(Pb)[(wr * 4 + mf) * 512 + lane8];       \
            al[mf] = *(const half8*)&(Pb)[(8 + wr * 4 + mf) * 512 + lane8];   \
        }                                                                     \
        _Pragma("unroll")                                                     \
        for (int nf = 0; nf < 2; ++nf)                                        \
            bh[nf] = *(const half8*)&(Pb)[(16 + wc * 2 + nf) * 512 + lane8];  \
        _Pragma("unroll")                                                     \
        for (int mf = 0; mf < 4; ++mf)                                        \
        _Pragma("unroll")                                                     \
            for (int nf = 0; nf < 2; ++nf) {                                  \
                acc[mf][nf] = __builtin_amdgcn_mfma_f32_16x16x32_f16(         \
                    ah[mf], bh[nf], acc[mf][nf], 0, 0, 0);                    \
                acc[mf][nf] = __builtin_amdgcn_mfma_f32_16x16x32_f16(         \
                    al[mf], bh[nf], acc[mf][nf], 0, 0, 0);                    \
            }                                                                 \
    } while (0)

    f32x4 acc[4][2];
#pragma unroll
    for (int mf = 0; mf < 4; ++mf)
#pragma unroll
        for (int nf = 0; nf < 2; ++nf) acc[mf][nf] = (f32x4)0.0f;

    PSTAGE(P[0], 0);
    __syncthreads();

#pragma unroll 1
    for (int it = 0; it < 8; ++it) {
        PSTAGE(P[1], it * 64 + 32);
        PCOMP(P[0]);
        __syncthreads();
        if (it < 7) PSTAGE(P[0], it * 64 + 64);
        PCOMP(P[1]);
        __syncthreads();
    }

    // epilogue: BN -> fp32 out. lane: col n=n0+wc*32+nf*16+lr,
    // row c=c0+wr*64+mf*16+4g+r.
    float* ob = out + (size_t)b * CC * NN;
#pragma unroll
    for (int mf = 0; mf < 4; ++mf) {
#pragma unroll
        for (int r = 0; r < 4; ++r) {
            const int c = c0 + wr * 64 + mf * 16 + 4 * g + r;
            const float gg = bn_g[3 * CC + c];
            const float bb = bn_b[3 * CC + c];
            const float mm = bn_m[3 * CC + c];
            const float vv = bn_v[3 * CC + c];
            const float inv = gg / sqrtf(vv + EPS);
            const float add = bb - mm * inv;
            ob[(size_t)c * NN + n0 + wc * 32 + lr]      = acc[mf][0][r] * inv + add;
            ob[(size_t)c * NN + n0 + wc * 32 + 16 + lr] = acc[mf][1][r] * inv + add;
        }
    }
#undef PSTAGE
#undef PCOMP
}

// ---------------------------------------------------------------------------
extern "C" void kernel_launch(void* const* d_in, const int* in_sizes, int n_in,
                              void* d_out, int out_size, void* d_ws, size_t ws_size,
                              hipStream_t stream) {
    const float* x     = (const float*)d_in[0];
    const float* wq    = (const float*)d_in[1];
    const float* wk    = (const float*)d_in[2];
    const float* wv    = (const float*)d_in[3];
    const float* wproj = (const float*)d_in[4];
    const float* bng   = (const float*)d_in[5];
    const float* bnb   = (const float*)d_in[6];
    const float* bnm   = (const float*)d_in[7];
    const float* bnv   = (const float*)d_in[8];

    // ws layout (bytes):
    //  [0,8M): packed spikes qp/kp/vp/s3p (2 MiB each)
    //  [8M): Wh [4][512][512] fp16 (2M), [10M): Wl (2M)
    //  [12M): XTh [64][512][512] fp16 (32M) -- reused as XSp after conv
    //  [44M): XTl (32M)                     -> ~76 MiB total
    uint8_t* ws = (uint8_t*)d_ws;
    const size_t PK = (size_t)BB * CC * NW;
    uint32_t* qp  = (uint32_t*)ws;
    uint32_t* kp  = qp + PK;
    uint32_t* vp  = kp + PK;
    uint32_t* s3p = vp + PK;
    _Float16* Wh  = (_Float16*)(ws + ((size_t)8  << 20));
    _Float16* Wl  = (_Float16*)(ws + ((size_t)10 << 20));
    _Float16* XTh = (_Float16*)(ws + ((size_t)12 << 20));
    _Float16* XTl = (_Float16*)(ws + ((size_t)44 << 20));
    _Float16* XSp = XTh;   // conv consumed XTh before unpack writes it

    split_w_kernel<<<1024, 256, 0, stream>>>(wq, wk, wv, wproj, Wh, Wl);
    split_xt_kernel<<<dim3(8, 8, BB), 256, 0, stream>>>(x, XTh, XTl);

    dim3 gconv(NN / 64, CC / 128, 3 * BE);             // z = w*16 + be
    conv_mfma_kernel<<<gconv, 256, 0, stream>>>(Wh, Wl, XTh, XTl,
                                                bng, bnb, bnm, bnv, qp, kp, vp);

    dim3 gattn(4, NH, BE);
    attn_lif_kernel<<<gattn, 256, 0, stream>>>(qp, kp, vp, s3p);

    unpack_kernel<<<dim3(CC / 64, BB), 256, 0, stream>>>(s3p, XSp);

    dim3 gproj(NN / 64, CC / 128, BB);
    proj_mfma_kernel<<<gproj, 256, 0, stream>>>(Wh, Wl, XSp,
                                                bng, bnb, bnm, bnv, (float*)d_out);
}

// Round 7
// 713.814 us; speedup vs baseline: 2.2606x; 1.0647x over previous
//
#include <hip/hip_runtime.h>
#include <hip/hip_bf16.h>
#include <stdint.h>

// Problem constants
#define TT 4
#define BE 16
#define BB 64          // TT * BE
#define CC 512
#define NN 512
#define NH 8
#define GD 64          // CC / NH
#define NW 16          // NN/32 packed words per (b,c) row
#define TAU 0.5f
#define THRESH 1.0f
#define SCALE 0.125f
#define EPS 1e-5f

typedef _Float16 half8 __attribute__((ext_vector_type(8)));
typedef _Float16 half4 __attribute__((ext_vector_type(4)));
typedef float    f32x4 __attribute__((ext_vector_type(4)));

// Direct global->LDS DMA, 16B per lane: lane l writes base + l*16.
#define GLL16(g, l)                                                        \
    __builtin_amdgcn_global_load_lds(                                      \
        (const __attribute__((address_space(1))) void*)(g),                \
        (__attribute__((address_space(3))) void*)(l), 16, 0, 0)

// ---------------------------------------------------------------------------
// split_w: Wq/Wk/Wv/Wproj fp32 [C][K] -> Wh/Wl fp16 pieces [4][C][K].
// ---------------------------------------------------------------------------
__global__ __launch_bounds__(256) void split_w_kernel(
    const float* __restrict__ wq, const float* __restrict__ wk,
    const float* __restrict__ wv, const float* __restrict__ wp,
    _Float16* __restrict__ Wh, _Float16* __restrict__ Wl)
{
    const int gid = blockIdx.x * 256 + threadIdx.x;      // 262144 threads
    const size_t e0 = (size_t)gid * 4;
    const int mat = (int)(e0 >> 18);
    const size_t off = e0 & 262143;
    const float* src = (mat == 0) ? wq : (mat == 1) ? wk : (mat == 2) ? wv : wp;
    float4 v = *(const float4*)&src[off];
    half4 h, l;
    h[0] = (_Float16)v.x; l[0] = (_Float16)(v.x - (float)h[0]);
    h[1] = (_Float16)v.y; l[1] = (_Float16)(v.y - (float)h[1]);
    h[2] = (_Float16)v.z; l[2] = (_Float16)(v.z - (float)h[2]);
    h[3] = (_Float16)v.w; l[3] = (_Float16)(v.w - (float)h[3]);
    *(half4*)&Wh[e0] = h;
    *(half4*)&Wl[e0] = l;
}

// ---------------------------------------------------------------------------
// split_xt: x fp32 [b][k][n] -> XTh/XTl fp16 TRANSPOSED [b][n][k].
// ---------------------------------------------------------------------------
__global__ __launch_bounds__(256) void split_xt_kernel(
    const float* __restrict__ x,
    _Float16* __restrict__ XTh, _Float16* __restrict__ XTl)
{
    __shared__ float Ls[64][68];
    const int tid = threadIdx.x;
    const int b  = blockIdx.z;
    const int k0 = blockIdx.y * 64;
    const int n0 = blockIdx.x * 64;
    const float* xb = x + ((size_t)b * CC + k0) * NN + n0;

    const int kr = tid >> 4;
    const int f4 = tid & 15;
#pragma unroll
    for (int i = 0; i < 4; ++i) {
        float4 v = *(const float4*)&xb[(size_t)(kr + 16 * i) * NN + f4 * 4];
        *(float4*)&Ls[kr + 16 * i][f4 * 4] = v;
    }
    __syncthreads();

    const int nr = tid >> 2;
    const int ks = tid & 3;
    half8 h0, h1, l0, l1;
#pragma unroll
    for (int j = 0; j < 8; ++j) {
        float v = Ls[ks * 16 + j][nr];
        _Float16 h = (_Float16)v;
        h0[j] = h; l0[j] = (_Float16)(v - (float)h);
    }
#pragma unroll
    for (int j = 0; j < 8; ++j) {
        float v = Ls[ks * 16 + 8 + j][nr];
        _Float16 h = (_Float16)v;
        h1[j] = h; l1[j] = (_Float16)(v - (float)h);
    }
    const size_t o = ((size_t)b * NN + n0 + nr) * CC + k0 + ks * 16;
    *(half8*)&XTh[o] = h0; *(half8*)&XTh[o + 8] = h1;
    *(half8*)&XTl[o] = l0; *(half8*)&XTl[o + 8] = l1;
}

// ---------------------------------------------------------------------------
// Kernel 1 v8: conv+BN+LIF via fp16-split MFMA, t-batch 2 + XCD swizzle.
// vs v7 (434us, conflicts 0, staging-wall ~2700cyc/stage):
//  * t-pair per k-stage: W tile staged ONCE serves 2 t's -> 32KB/stage for
//    2x MFMA (bytes/MFMA 256->167); stages/block 64->32.
//  * A-frags (W) read once per stage, held across the t-pair (halves LDS
//    read traffic vs re-read).
//  * XCD-chunked swizzle: contiguous 192-block ranges per XCD -> the 8
//    n0-neighbors sharing a W tile hit the same XCD L2, not L3.
//  * Schedule stays v6's proven 2-barrier single-buffer (no prefetch: every
//    pipelined variant blew regalloc). LIF mem carries across the t-pairs.
// ---------------------------------------------------------------------------
__global__ __launch_bounds__(256) void conv_mfma_kernel(
    const _Float16* __restrict__ Wh,   // [4][CC][CC]
    const _Float16* __restrict__ Wl,
    const _Float16* __restrict__ XTh,  // [BB][NN][CC]
    const _Float16* __restrict__ XTl,
    const float* __restrict__ bn_g,    // [4][CC]
    const float* __restrict__ bn_b,
    const float* __restrict__ bn_m,
    const float* __restrict__ bn_v,
    uint32_t* __restrict__ qp,
    uint32_t* __restrict__ kp,
    uint32_t* __restrict__ vp)
{
    __shared__ _Float16 T[32 * 512];   // 32 slots x 1KB = 32 KB

    const int tid = threadIdx.x;
    const int lane = tid & 63;
    const int wid  = tid >> 6;        // 0..3
    const int wr = wid >> 1;          // c-half of 128-row tile
    const int wc = wid & 1;           // n-half of 64-col tile
    const int lr = lane & 15;
    const int g  = lane >> 4;
    const int lane8 = lane * 8;

    // XCD-chunked swizzle: hw id -> logical tile; 1536 = 8 XCD x 192
    const int hw = blockIdx.x + (blockIdx.y << 3) + (blockIdx.z << 5);
    const int lg = (hw & 7) * 192 + (hw >> 3);
    const int n0 = (lg & 7) * 64;
    const int c0 = ((lg >> 3) & 3) * 128;
    const int z  = lg >> 5;           // 0..47
    const int be = z & (BE - 1);
    const int wmat = z >> 4;          // 0=q 1=k 2=v

    uint32_t* outp = (wmat == 0) ? qp : (wmat == 1) ? kp : vp;

    // fragment-order staging source (verified v7): lane -> (row lane&15,
    // k-quarter lane>>4); linear LDS dest IS fragment order.
    const _Float16* pWh = Wh + (size_t)wmat * CC * CC + (size_t)(c0 + lr) * CC + g * 8;
    const _Float16* pWl = Wl + (size_t)wmat * CC * CC + (size_t)(c0 + lr) * CC + g * 8;
    const size_t tstep = (size_t)BE * NN * CC;   // halfs between consecutive t

    f32x4 mem[4][2];
#pragma unroll
    for (int mf = 0; mf < 4; ++mf)
#pragma unroll
        for (int nf = 0; nf < 2; ++nf) mem[mf][nf] = (f32x4)0.0f;

#pragma unroll 1
    for (int tp = 0; tp < 2; ++tp) {
        const int b0 = (2 * tp) * BE + be;
        const _Float16* pXh0 = XTh + ((size_t)b0 * NN + n0 + lr) * CC + g * 8;
        const _Float16* pXl0 = XTl + ((size_t)b0 * NN + n0 + lr) * CC + g * 8;

        f32x4 acc[2][4][2];
#pragma unroll
        for (int tl = 0; tl < 2; ++tl)
#pragma unroll
            for (int mf = 0; mf < 4; ++mf)
#pragma unroll
                for (int nf = 0; nf < 2; ++nf) acc[tl][mf][nf] = (f32x4)0.0f;

#pragma unroll 1
        for (int kt = 0; kt < 16; ++kt) {
            const int k0 = kt * 32;
            __syncthreads();   // seal previous stage's T readers
            // W: slots 0..7 = Wh rows, 8..15 = Wl rows (4 glls/wave)
            GLL16(pWh + (size_t)(wid * 16) * CC + k0,       &T[(wid +  0) * 512]);
            GLL16(pWh + (size_t)((wid + 4) * 16) * CC + k0, &T[(wid +  4) * 512]);
            GLL16(pWl + (size_t)(wid * 16) * CC + k0,       &T[(wid +  8) * 512]);
            GLL16(pWl + (size_t)((wid + 4) * 16) * CC + k0, &T[(wid + 12) * 512]);
            // X: slots 16..19 Xh(t0), 20..23 Xl(t0), 24..27 Xh(t1), 28..31 Xl(t1)
            GLL16(pXh0 + (size_t)(wid * 16) * CC + k0,         &T[(16 + wid) * 512]);
            GLL16(pXl0 + (size_t)(wid * 16) * CC + k0,         &T[(20 + wid) * 512]);
            GLL16(pXh0 + tstep + (size_t)(wid * 16) * CC + k0, &T[(24 + wid) * 512]);
            GLL16(pXl0 + tstep + (size_t)(wid * 16) * CC + k0, &T[(28 + wid) * 512]);
            __syncthreads();   // vmcnt drained: tile ready

            // A-frags once per stage, held across the t-pair
            half8 ah[4], al[4];
#pragma unroll
            for (int mf = 0; mf < 4; ++mf) {
                ah[mf] = *(const half8*)&T[(wr * 4 + mf) * 512 + lane8];
                al[mf] = *(const half8*)&T[(8 + wr * 4 + mf) * 512 + lane8];
            }
#pragma unroll
            for (int tl = 0; tl < 2; ++tl) {
                half8 bh[2], bl[2];
#pragma unroll
                for (int nf = 0; nf < 2; ++nf) {
                    bh[nf] = *(const half8*)&T[(16 + tl * 8 + wc * 2 + nf) * 512 + lane8];
                    bl[nf] = *(const half8*)&T[(20 + tl * 8 + wc * 2 + nf) * 512 + lane8];
                }
#pragma unroll
                for (int mf = 0; mf < 4; ++mf)
#pragma unroll
                    for (int nf = 0; nf < 2; ++nf) {
                        acc[tl][mf][nf] = __builtin_amdgcn_mfma_f32_16x16x32_f16(
                            ah[mf], bh[nf], acc[tl][mf][nf], 0, 0, 0);
                        acc[tl][mf][nf] = __builtin_amdgcn_mfma_f32_16x16x32_f16(
                            ah[mf], bl[nf], acc[tl][mf][nf], 0, 0, 0);
                        acc[tl][mf][nf] = __builtin_amdgcn_mfma_f32_16x16x32_f16(
                            al[mf], bh[nf], acc[tl][mf][nf], 0, 0, 0);
                    }
            }
        }

        // epilogue: per t of the pair, BN + LIF -> pack (mem carries on)
        const int nword = (n0 >> 5) + wc;
#pragma unroll
        for (int tl = 0; tl < 2; ++tl) {
            const int b = b0 + tl * BE;
#pragma unroll
            for (int mf = 0; mf < 4; ++mf) {
#pragma unroll
                for (int r = 0; r < 4; ++r) {
                    const int c = c0 + wr * 64 + mf * 16 + 4 * g + r;
                    const float gg = bn_g[wmat * CC + c];
                    const float bb = bn_b[wmat * CC + c];
                    const float mm = bn_m[wmat * CC + c];
                    const float vv = bn_v[wmat * CC + c];
                    const float inv = gg / sqrtf(vv + EPS);
                    const float add = bb - mm * inv;

                    float y0 = acc[tl][mf][0][r] * inv + add;
                    float m0 = mem[mf][0][r] * TAU + y0;
                    bool s0 = m0 > THRESH;
                    mem[mf][0][r] = s0 ? 0.0f : m0;

                    float y1 = acc[tl][mf][1][r] * inv + add;
                    float m1 = mem[mf][1][r] * TAU + y1;
                    bool s1 = m1 > THRESH;
                    mem[mf][1][r] = s1 ? 0.0f : m1;

                    uint32_t wbits = ((s0 ? 1u : 0u) << lr) |
                                     ((s1 ? 1u : 0u) << (16 + lr));
                    wbits |= (uint32_t)__shfl_xor((int)wbits, 1);
                    wbits |= (uint32_t)__shfl_xor((int)wbits, 2);
                    wbits |= (uint32_t)__shfl_xor((int)wbits, 4);
                    wbits |= (uint32_t)__shfl_xor((int)wbits, 8);
                    if (lr == 0) {
                        outp[(size_t)(b * CC + c) * NW + nword] = wbits;
                    }
                }
            }
        }
    }
}

// ---------------------------------------------------------------------------
// Kernel 2: fused attention + LIF3 on packed spikes (unchanged, verified).
// ---------------------------------------------------------------------------
__global__ __launch_bounds__(256) void attn_lif_kernel(
    const uint32_t* __restrict__ qp,
    const uint32_t* __restrict__ kp,
    const uint32_t* __restrict__ vp,
    uint32_t* __restrict__ s3p)
{
    __shared__ uint32_t kL[64][NW + 1];
    __shared__ uint32_t vL[64][NW + 1];
    __shared__ float    Msh[64][64 + 1];
    __shared__ uint32_t qL[64][5];

    const int tid = threadIdx.x;
    const int nchunk = blockIdx.x;
    const int h = blockIdx.y;
    const int be = blockIdx.z;
    const int d_own = tid >> 2;
    const int nw_own = tid & 3;

    float mem[32];
#pragma unroll
    for (int i = 0; i < 32; ++i) mem[i] = 0.0f;

    for (int t = 0; t < TT; ++t) {
        const int b = t * BE + be;
        const size_t base_row = (size_t)(b * CC + h * GD);

        for (int i = tid; i < 64 * NW; i += 256) {
            int r = i >> 4;
            int w = i & (NW - 1);
            kL[r][w] = kp[(base_row + r) * NW + w];
            vL[r][w] = vp[(base_row + r) * NW + w];
        }
        {
            int r = tid >> 2;
            int w = tid & 3;
            qL[r][w] = qp[(base_row + r) * NW + nchunk * 4 + w];
        }
        __syncthreads();

        for (int e = tid; e < 64 * 64; e += 256) {
            int d = e >> 6;
            int dp = e & 63;
            int s = 0;
#pragma unroll
            for (int w = 0; w < NW; ++w) s += __popc(vL[d][w] & kL[dp][w]);
            Msh[d][dp] = (float)s;
        }
        __syncthreads();

        float acc[32];
#pragma unroll
        for (int i = 0; i < 32; ++i) acc[i] = 0.0f;

        for (int dp = 0; dp < 64; ++dp) {
            float Mv = Msh[d_own][dp];
            uint32_t w = qL[dp][nw_own];
#pragma unroll
            for (int b2 = 0; b2 < 32; ++b2) {
                acc[b2] += ((w >> b2) & 1u) ? Mv : 0.0f;
            }
        }

        uint32_t sw = 0;
#pragma unroll
        for (int b2 = 0; b2 < 32; ++b2) {
            float m2 = mem[b2] * TAU + SCALE * acc[b2];
            bool s = m2 > THRESH;
            sw |= (s ? 1u : 0u) << b2;
            mem[b2] = s ? 0.0f : m2;
        }
        s3p[(base_row + d_own) * NW + nchunk * 4 + nw_own] = sw;
        __syncthreads();
    }
}

// ---------------------------------------------------------------------------
// unpack: s3p packed spikes -> XSp fp16 [b][n][k=c].
// ---------------------------------------------------------------------------
__global__ __launch_bounds__(256) void unpack_kernel(
    const uint32_t* __restrict__ s3p, _Float16* __restrict__ XSp)
{
    __shared__ uint32_t Wd[64][NW + 1];
    const int tid = threadIdx.x;
    const int c0 = blockIdx.x * 64;
    const int b  = blockIdx.y;
    const uint32_t* sp = s3p + ((size_t)b * CC + c0) * NW;

#pragma unroll
    for (int s = 0; s < 4; ++s) {
        int i = tid + s * 256;
        Wd[i >> 4][i & 15] = sp[i];
    }
    __syncthreads();

#pragma unroll
    for (int s = 0; s < 2; ++s) {
        const int n = tid + s * 256;
        const int nw = n >> 5, bit = n & 31;
        _Float16* dst = XSp + ((size_t)b * NN + n) * CC + c0;
#pragma unroll
        for (int c8 = 0; c8 < 8; ++c8) {
            half8 h;
#pragma unroll
            for (int j = 0; j < 8; ++j)
                h[j] = ((Wd[c8 * 8 + j][nw] >> bit) & 1u) ? (_Float16)1.0f
                                                          : (_Float16)0.0f;
            *(half8*)&dst[c8 * 8] = h;
        }
    }
}

// ---------------------------------------------------------------------------
// Kernel 3 v5: projection conv + BN via MFMA, b-batch 2 + XCD swizzle.
// W tile staged once per stage serves 2 b's (24KB/stage for 2x MFMA);
// A-frags held across the pair. Grid (8, 4, 32): z = b-pair.
// ---------------------------------------------------------------------------
__global__ __launch_bounds__(256) void proj_mfma_kernel(
    const _Float16* __restrict__ Wh,   // [4][CC][CC], uses mat 3
    const _Float16* __restrict__ Wl,
    const _Float16* __restrict__ XSp,  // [BB][NN][CC]
    const float* __restrict__ bn_g,
    const float* __restrict__ bn_b,
    const float* __restrict__ bn_m,
    const float* __restrict__ bn_v,
    float* __restrict__ out)           // [BB][CC][NN]
{
    __shared__ _Float16 P[24 * 512];   // 24 KB

    const int tid = threadIdx.x;
    const int lane = tid & 63;
    const int wid  = tid >> 6;
    const int wr = wid >> 1;
    const int wc = wid & 1;
    const int lr = lane & 15;
    const int g  = lane >> 4;
    const int lane8 = lane * 8;

    // XCD-chunked swizzle: 1024 = 8 XCD x 128
    const int hw = blockIdx.x + (blockIdx.y << 3) + (blockIdx.z << 5);
    const int lg = (hw & 7) * 128 + (hw >> 3);
    const int n0 = (lg & 7) * 64;
    const int c0 = ((lg >> 3) & 3) * 128;
    const int b0 = (lg >> 5) * 2;     // b-pair {b0, b0+1}

    const _Float16* pWh = Wh + (size_t)3 * CC * CC + (size_t)(c0 + lr) * CC + g * 8;
    const _Float16* pWl = Wl + (size_t)3 * CC * CC + (size_t)(c0 + lr) * CC + g * 8;
    const _Float16* pX0 = XSp + ((size_t)b0 * NN + n0 + lr) * CC + g * 8;
    const size_t bstep = (size_t)NN * CC;

    f32x4 acc[2][4][2];
#pragma unroll
    for (int bl = 0; bl < 2; ++bl)
#pragma unroll
        for (int mf = 0; mf < 4; ++mf)
#pragma unroll
            for (int nf = 0; nf < 2; ++nf) acc[bl][mf][nf] = (f32x4)0.0f;

#pragma unroll 1
    for (int kt = 0; kt < 16; ++kt) {
        const int k0 = kt * 32;
        __syncthreads();
        GLL16(pWh + (size_t)(wid * 16) * CC + k0,       &P[(wid +  0) * 512]);
        GLL16(pWh + (size_t)((wid + 4) * 16) * CC + k0, &P[(wid +  4) * 512]);
        GLL16(pWl + (size_t)(wid * 16) * CC + k0,       &P[(wid +  8) * 512]);
        GLL16(pWl + (size_t)((wid + 4) * 16) * CC + k0, &P[(wid + 12) * 512]);
        GLL16(pX0 + (size_t)(wid * 16) * CC + k0,         &P[(16 + wid) * 512]);
        GLL16(pX0 + bstep + (size_t)(wid * 16) * CC + k0, &P[(20 + wid) * 512]);
        __syncthreads();

        half8 ah[4], al[4];
#pragma unroll
        for (int mf = 0; mf < 4; ++mf) {
            ah[mf] = *(const half8*)&P[(wr * 4 + mf) * 512 + lane8];
            al[mf] = *(const half8*)&P[(8 + wr * 4 + mf) * 512 + lane8];
        }
#pragma unroll
        for (int bl = 0; bl < 2; ++bl) {
            half8 bh[2];
#pragma unroll
            for (int nf = 0; nf < 2; ++nf)
                bh[nf] = *(const half8*)&P[(16 + bl * 4 + wc * 2 + nf) * 512 + lane8];
#pragma unroll
            for (int mf = 0; mf < 4; ++mf)
#pragma unroll
                for (int nf = 0; nf < 2; ++nf) {
                    acc[bl][mf][nf] = __builtin_amdgcn_mfma_f32_16x16x32_f16(
                        ah[mf], bh[nf], acc[bl][mf][nf], 0, 0, 0);
                    acc[bl][mf][nf] = __builtin_amdgcn_mfma_f32_16x16x32_f16(
                        al[mf], bh[nf], acc[bl][mf][nf], 0, 0, 0);
                }
        }
    }

    // epilogue: BN -> fp32 out for both b's
#pragma unroll
    for (int bl = 0; bl < 2; ++bl) {
        float* ob = out + (size_t)(b0 + bl) * CC * NN;
#pragma unroll
        for (int mf = 0; mf < 4; ++mf) {
#pragma unroll
            for (int r = 0; r < 4; ++r) {
                const int c = c0 + wr * 64 + mf * 16 + 4 * g + r;
                const float gg = bn_g[3 * CC + c];
                const float bb = bn_b[3 * CC + c];
                const float mm = bn_m[3 * CC + c];
                const float vv = bn_v[3 * CC + c];
                const float inv = gg / sqrtf(vv + EPS);
                const float add = bb - mm * inv;
                ob[(size_t)c * NN + n0 + wc * 32 + lr]      = acc[bl][mf][0][r] * inv + add;
                ob[(size_t)c * NN + n0 + wc * 32 + 16 + lr] = acc[bl][mf][1][r] * inv + add;
            }
        }
    }
}

// ---------------------------------------------------------------------------
extern "C" void kernel_launch(void* const* d_in, const int* in_sizes, int n_in,
                              void* d_out, int out_size, void* d_ws, size_t ws_size,
                              hipStream_t stream) {
    const float* x     = (const float*)d_in[0];
    const float* wq    = (const float*)d_in[1];
    const float* wk    = (const float*)d_in[2];
    const float* wv    = (const float*)d_in[3];
    const float* wproj = (const float*)d_in[4];
    const float* bng   = (const float*)d_in[5];
    const float* bnb   = (const float*)d_in[6];
    const float* bnm   = (const float*)d_in[7];
    const float* bnv   = (const float*)d_in[8];

    // ws layout (bytes):
    //  [0,8M): packed spikes qp/kp/vp/s3p (2 MiB each)
    //  [8M): Wh [4][512][512] fp16 (2M), [10M): Wl (2M)
    //  [12M): XTh [64][512][512] fp16 (32M) -- reused as XSp after conv
    //  [44M): XTl (32M)
    uint8_t* ws = (uint8_t*)d_ws;
    const size_t PK = (size_t)BB * CC * NW;
    uint32_t* qp  = (uint32_t*)ws;
    uint32_t* kp  = qp + PK;
    uint32_t* vp  = kp + PK;
    uint32_t* s3p = vp + PK;
    _Float16* Wh  = (_Float16*)(ws + ((size_t)8  << 20));
    _Float16* Wl  = (_Float16*)(ws + ((size_t)10 << 20));
    _Float16* XTh = (_Float16*)(ws + ((size_t)12 << 20));
    _Float16* XTl = (_Float16*)(ws + ((size_t)44 << 20));
    _Float16* XSp = XTh;   // conv consumed XTh before unpack writes it

    split_w_kernel<<<1024, 256, 0, stream>>>(wq, wk, wv, wproj, Wh, Wl);
    split_xt_kernel<<<dim3(8, 8, BB), 256, 0, stream>>>(x, XTh, XTl);

    dim3 gconv(NN / 64, CC / 128, 3 * BE);             // hw grid; swizzled inside
    conv_mfma_kernel<<<gconv, 256, 0, stream>>>(Wh, Wl, XTh, XTl,
                                                bng, bnb, bnm, bnv, qp, kp, vp);

    dim3 gattn(4, NH, BE);
    attn_lif_kernel<<<gattn, 256, 0, stream>>>(qp, kp, vp, s3p);

    unpack_kernel<<<dim3(CC / 64, BB), 256, 0, stream>>>(s3p, XSp);

    dim3 gproj(NN / 64, CC / 128, BB / 2);             // z = b-pair
    proj_mfma_kernel<<<gproj, 256, 0, stream>>>(Wh, Wl, XSp,
                                                bng, bnb, bnm, bnv, (float*)d_out);
}